// Round 14
// baseline (365.788 us; speedup 1.0000x reference)
//
#include <hip/hip_runtime.h>

#define B_ 4
#define NH_ 32
#define SQ_ 512
#define HD_ 128
#define MLEN_ 3584
#define KT_ 4096           // MLEN_ + SQ_
#define QB_ 128
#define KB_ 32
#define NTILE_ 128         // KT_ / KB_
#define MEMTILES_ 112      // MLEN_ / KB_
#define HTILES_ 64         // NTILE_ / 2 per split half

typedef float f32x4 __attribute__((ext_vector_type(4)));
typedef short s16x8 __attribute__((ext_vector_type(8)));

__device__ __forceinline__ f32x4 MFMA16(s16x8 a, s16x8 b, f32x4 c) {
    return __builtin_amdgcn_mfma_f32_16x16x32_bf16(a, b, c, 0, 0, 0);
}

__device__ __forceinline__ s16x8 cvt8(float4 a, float4 b) {
    union { s16x8 v; __bf16 h[8]; } u;
    u.h[0] = (__bf16)a.x; u.h[1] = (__bf16)a.y;
    u.h[2] = (__bf16)a.z; u.h[3] = (__bf16)a.w;
    u.h[4] = (__bf16)b.x; u.h[5] = (__bf16)b.y;
    u.h[6] = (__bf16)b.z; u.h[7] = (__bf16)b.w;
    return u.v;
}

// 4 waves x 32 q-rows (halved LDS-read traffic: every kf/vf feeds 2 MFMAs)
// x split-KV 2-way (grid 1024 -> 4 blocks/CU = 16 waves/CU, 4 barrier domains).
// Single 16KB LDS buffer, no prefetch (R7-R12: all pipelining attempts were
// neutral or spilled). R12 proved VGPR~104 -> 4 waves/SIMD legal; R13 proved
// split-KV correctness + cheap reduce. This is the first config with BOTH
// halved traffic AND 16 waves/CU.
__launch_bounds__(256, 2)
__global__ void attn_split_kernel(const float* __restrict__ q, const float* __restrict__ k,
                                  const float* __restrict__ v, const float* __restrict__ mask,
                                  const float* __restrict__ mem,
                                  float* __restrict__ opart, float2* __restrict__ ml)
{
    __shared__ __bf16 Kb[KB_ * HD_];        // 8 KB, swizzled rows (256B rows)
    __shared__ __bf16 Vtb[HD_ * KB_];       // 8 KB, transposed (64B rows)

    const int tid  = threadIdx.x;
    const int lane = tid & 63;
    const int w    = tid >> 6;              // 0..3
    const int l15  = lane & 15;
    const int l4   = lane >> 4;             // 0..3
    const int xv   = (lane & 7) << 4;       // K-row swizzle key

    // bid: [half:1][qt:2][bh:7] -> same head's blocks bid%128-equal (same XCD)
    const int half = blockIdx.x >> 9;
    const int qt   = (blockIdx.x >> 7) & 3;
    const int pair = blockIdx.x & 127;
    const int b    = pair >> 5;
    const int h    = pair & 31;
    const int q0   = qt * QB_;
    const int t0   = half * HTILES_;

    // ---- Q fragments, m = 0,1 row-subtiles; wave rows q0 + w*32 + m*16 + l15 ----
    const float scale = 0.088388347648318447f;   // 1/sqrt(128)
    s16x8 qf[2][4];
    {
        const float* qbase = q + (((size_t)(b * NH_ + h)) * SQ_ + q0 + w * 32 + l15) * HD_;
        #pragma unroll
        for (int m = 0; m < 2; ++m)
            #pragma unroll
            for (int kc = 0; kc < 4; ++kc) {
                const float* p = qbase + (size_t)m * 16 * HD_ + kc * 32 + l4 * 8;
                float4 a = *(const float4*)p;
                float4 c = *(const float4*)(p + 4);
                a.x *= scale; a.y *= scale; a.z *= scale; a.w *= scale;
                c.x *= scale; c.y *= scale; c.z *= scale; c.w *= scale;
                qf[m][kc] = cvt8(a, c);
            }
    }

    f32x4 acc[2][8];
    #pragma unroll
    for (int m = 0; m < 2; ++m)
        #pragma unroll
        for (int n = 0; n < 8; ++n) acc[m][n] = (f32x4){0.f, 0.f, 0.f, 0.f};

    float mrun[2] = {-3.0e38f, -3.0e38f}, lrun[2] = {0.f, 0.f};

    const float* maskrow = mask + ((size_t)b * SQ_ + q0 + w * 32 + l15) * KT_;

    const int krow = tid >> 4,  kcg  = tid & 15;   // K unit: rows 0..15 (+16 it1)
    const int vhd  = tid & 127, vkvb = tid >> 7;   // V unit: kvb {0,1} (+2 it1)
    const int vsw  = (vhd >> 1) & 3;               // V^T write-slot key

    for (int t = t0; t < t0 + HTILES_; ++t) {
        const int kv0 = t * KB_;
        const float *srcK, *srcV;
        int rs;
        if (t < MEMTILES_) {
            const float* mrow = mem + ((size_t)b * MLEN_ + kv0) * (2 * NH_ * HD_) + h * HD_;
            srcK = mrow;
            srcV = mrow + NH_ * HD_;
            rs = 2 * NH_ * HD_;
        } else {
            size_t off = (((size_t)b * NH_ + h) * SQ_ + (kv0 - MLEN_)) * HD_;
            srcK = k + off;
            srcV = v + off;
            rs = HD_;
        }

        __syncthreads();   // previous tile's LDS reads complete

        // ---- K stage: 512 x 16B chunks over 256 threads ----
        #pragma unroll
        for (int it = 0; it < 2; ++it) {
            int row = krow + it * 16;
            const float* p = srcK + (size_t)row * rs + kcg * 8;
            float4 a = *(const float4*)p;
            float4 c = *(const float4*)(p + 4);
            int byte = row * 256 + ((kcg * 16) ^ ((row & 7) << 4));
            *(s16x8*)((char*)Kb + byte) = cvt8(a, c);
        }
        // ---- V stage (transposed, 64B rows) ----
        #pragma unroll
        for (int it = 0; it < 2; ++it) {
            int kvb = vkvb + it * 2;
            const float* p = srcV + (size_t)(kvb * 8) * rs + vhd;
            union { s16x8 v; __bf16 hh[8]; } u;
            #pragma unroll
            for (int j = 0; j < 8; ++j) u.hh[j] = (__bf16)p[(size_t)j * rs];
            int byte = vhd * 64 + (((kvb ^ vsw) & 3) << 4);
            *(s16x8*)((char*)Vtb + byte) = u.v;
        }

        // ---- mask loads (drain with the stage at the barrier) ----
        f32x4 mk[2][2];
        #pragma unroll
        for (int m = 0; m < 2; ++m)
            #pragma unroll
            for (int mt = 0; mt < 2; ++mt)
                mk[m][mt] = *(const f32x4*)(maskrow + (size_t)m * 16 * KT_ +
                                            kv0 + mt * 16 + l4 * 4);

        __syncthreads();   // tile staged

        // ---- S^T = K @ Q^T : st[m][mt], rows kv = mt*16+l4*4+r, cols q-sub l15 ----
        f32x4 st[2][2];
        st[0][0] = (f32x4){0.f,0.f,0.f,0.f}; st[0][1] = (f32x4){0.f,0.f,0.f,0.f};
        st[1][0] = (f32x4){0.f,0.f,0.f,0.f}; st[1][1] = (f32x4){0.f,0.f,0.f,0.f};
        __builtin_amdgcn_s_setprio(1);
        #pragma unroll
        for (int mt = 0; mt < 2; ++mt) {
            #pragma unroll
            for (int kc = 0; kc < 4; ++kc) {
                s16x8 kf = *(const s16x8*)((const char*)Kb +
                            (mt * 16 + l15) * 256 + (((kc * 4 + l4) * 16) ^ xv));
                st[0][mt] = MFMA16(kf, qf[0][kc], st[0][mt]);
                st[1][mt] = MFMA16(kf, qf[1][kc], st[1][mt]);
            }
        }
        __builtin_amdgcn_s_setprio(0);

        // ---- mask + softmax + pack, per m ----
        s16x8 pa[2];
        #pragma unroll
        for (int m = 0; m < 2; ++m) {
            #pragma unroll
            for (int mt = 0; mt < 2; ++mt)
                #pragma unroll
                for (int r = 0; r < 4; ++r)
                    st[m][mt][r] = fmaf(mk[m][mt][r], st[m][mt][r] + 10000.f, -10000.f);

            float rm = fmaxf(fmaxf(fmaxf(st[m][0][0], st[m][0][1]),
                                   fmaxf(st[m][0][2], st[m][0][3])),
                             fmaxf(fmaxf(st[m][1][0], st[m][1][1]),
                                   fmaxf(st[m][1][2], st[m][1][3])));
            rm = fmaxf(rm, __shfl_xor(rm, 16));
            rm = fmaxf(rm, __shfl_xor(rm, 32));

            if (!__all(rm <= mrun[m] + 8.f)) {    // defer-max
                float nm = fmaxf(mrun[m], rm);
                float al = __expf(mrun[m] - nm);
                mrun[m] = nm;
                lrun[m] *= al;
                float a0 = __shfl(al, l4 * 4 + 0);
                float a1 = __shfl(al, l4 * 4 + 1);
                float a2 = __shfl(al, l4 * 4 + 2);
                float a3 = __shfl(al, l4 * 4 + 3);
                #pragma unroll
                for (int nn = 0; nn < 8; ++nn) {
                    acc[m][nn][0] *= a0; acc[m][nn][1] *= a1;
                    acc[m][nn][2] *= a2; acc[m][nn][3] *= a3;
                }
            }

            float rsum = 0.f;
            #pragma unroll
            for (int mt = 0; mt < 2; ++mt)
                #pragma unroll
                for (int r = 0; r < 4; ++r) {
                    float pe = __expf(st[m][mt][r] - mrun[m]);
                    st[m][mt][r] = pe;
                    rsum += pe;
                }
            rsum += __shfl_xor(rsum, 16);
            rsum += __shfl_xor(rsum, 32);
            lrun[m] += rsum;

            union PK { int d[2]; __bf16 hh[4]; };
            PK pk0, pk1;
            pk0.hh[0]=(__bf16)st[m][0][0]; pk0.hh[1]=(__bf16)st[m][0][1];
            pk0.hh[2]=(__bf16)st[m][0][2]; pk0.hh[3]=(__bf16)st[m][0][3];
            pk1.hh[0]=(__bf16)st[m][1][0]; pk1.hh[1]=(__bf16)st[m][1][1];
            pk1.hh[2]=(__bf16)st[m][1][2]; pk1.hh[3]=(__bf16)st[m][1][3];

            const int srcA = (l4 & 1) * 32 + l15;
            const int srcB = srcA + 16;
            const int sel  = l4 >> 1;
            union { int d[4]; s16x8 v; } ua;
            int a0 = __shfl(pk0.d[0], srcA), a1 = __shfl(pk0.d[1], srcA);
            int b0 = __shfl(pk1.d[0], srcA), b1 = __shfl(pk1.d[1], srcA);
            int a2 = __shfl(pk0.d[0], srcB), a3 = __shfl(pk0.d[1], srcB);
            int b2 = __shfl(pk1.d[0], srcB), b3 = __shfl(pk1.d[1], srcB);
            ua.d[0] = sel ? b0 : a0; ua.d[1] = sel ? b1 : a1;
            ua.d[2] = sel ? b2 : a2; ua.d[3] = sel ? b3 : a3;
            pa[m] = ua.v;
        }

        // ---- O += P @ V : each vf read feeds BOTH m MFMAs ----
        __builtin_amdgcn_s_setprio(1);
        #pragma unroll
        for (int nn = 0; nn < 8; ++nn) {
            int hdv = nn * 16 + l15;
            s16x8 vf = *(const s16x8*)((const char*)Vtb +
                         hdv * 64 + (((l4 ^ ((hdv >> 1) & 3)) & 3) << 4));
            acc[0][nn] = MFMA16(pa[0], vf, acc[0][nn]);
            acc[1][nn] = MFMA16(pa[1], vf, acc[1][nn]);
        }
        __builtin_amdgcn_s_setprio(0);
    }

    // ---- epilogue: UNNORMALIZED partial O + per-row (m,l), per m-subtile ----
    #pragma unroll
    for (int m = 0; m < 2; ++m) {
        float* obase = opart + (size_t)half * (B_ * NH_ * SQ_ * HD_) +
                       (((size_t)(b * NH_ + h)) * SQ_ +
                        q0 + w * 32 + m * 16 + l4 * 4) * HD_ + l15;
        #pragma unroll
        for (int nn = 0; nn < 8; ++nn) {
            obase[(size_t)0 * HD_ + nn * 16] = acc[m][nn][0];
            obase[(size_t)1 * HD_ + nn * 16] = acc[m][nn][1];
            obase[(size_t)2 * HD_ + nn * 16] = acc[m][nn][2];
            obase[(size_t)3 * HD_ + nn * 16] = acc[m][nn][3];
        }
        if (l4 == 0) {
            int row = (b * NH_ + h) * SQ_ + q0 + w * 32 + m * 16 + l15;
            ml[half * (B_ * NH_ * SQ_) + row] = make_float2(mrun[m], lrun[m]);
        }
    }
}

// Combine the two KV-halves: O = (O0*e0 + O1*e1) / (l0*e0 + l1*e1)
__global__ void reduce_kernel(const float* __restrict__ part, const float2* __restrict__ ml,
                              float* __restrict__ ctx)
{
    int idx = blockIdx.x * 256 + threadIdx.x;
    int row = idx >> 5;
    int c4  = (idx & 31) * 4;
    float2 a = ml[row];
    float2 c = ml[(B_ * NH_ * SQ_) + row];
    float mm = fmaxf(a.x, c.x);
    float e0 = __expf(a.x - mm), e1 = __expf(c.x - mm);
    float inv = 1.f / (a.y * e0 + c.y * e1);
    const float4 o0 = *(const float4*)(part + (size_t)row * HD_ + c4);
    const float4 o1 = *(const float4*)(part + (size_t)(B_ * NH_ * SQ_) * HD_ +
                                       (size_t)row * HD_ + c4);
    float4 o;
    o.x = (o0.x * e0 + o1.x * e1) * inv;
    o.y = (o0.y * e0 + o1.y * e1) * inv;
    o.z = (o0.z * e0 + o1.z * e1) * inv;
    o.w = (o0.w * e0 + o1.w * e1) * inv;
    *(float4*)(ctx + (size_t)row * HD_ + c4) = o;
}

// cache_kv: out[b][s][part][h][d] = (part ? v : k)[b][h][s][d]
__global__ void cachekv_kernel(const float* __restrict__ k, const float* __restrict__ v,
                               float* __restrict__ out)
{
    size_t i = ((size_t)blockIdx.x * 256 + threadIdx.x) * 4;
    unsigned f = (unsigned)i;
    unsigned d    = f & 127;
    unsigned hh   = (f >> 7) & 31;
    unsigned part = (f >> 12) & 1;
    unsigned s    = (f >> 13) & 511;
    unsigned bb   = f >> 22;
    const float* src = (part ? v : k) + (((size_t)(bb * 32u + hh)) * 512u + s) * 128u + d;
    *(float4*)(out + i) = *(const float4*)src;
}

extern "C" void kernel_launch(void* const* d_in, const int* in_sizes, int n_in,
                              void* d_out, int out_size, void* d_ws, size_t ws_size,
                              hipStream_t stream) {
    const float* q    = (const float*)d_in[0];
    const float* k    = (const float*)d_in[1];
    const float* v    = (const float*)d_in[2];
    const float* mask = (const float*)d_in[3];
    const float* mem  = (const float*)d_in[4];
    float* out = (float*)d_out;

    const int ctx_elems = B_ * NH_ * SQ_ * HD_;                 // 8388608
    const int ckv_elems = B_ * SQ_ * 2 * NH_ * HD_;             // 16777216

    float*  part = out + ctx_elems;        // cachekv region doubles as partial-O
    float2* ml   = (float2*)d_ws;          // 2 * 65536 * 8B = 1 MB

    attn_split_kernel<<<dim3(2 * B_ * NH_ * (SQ_ / QB_)), dim3(256), 0, stream>>>(
        q, k, v, mask, mem, part, ml);

    reduce_kernel<<<dim3(ctx_elems / 4 / 256), dim3(256), 0, stream>>>(part, ml, out);

    cachekv_kernel<<<dim3(ckv_elems / 4 / 256), dim3(256), 0, stream>>>(k, v, out + ctx_elems);

    (void)in_sizes; (void)n_in; (void)out_size; (void)ws_size;
}